// Round 2
// baseline (71.723 us; speedup 1.0000x reference)
//
#include <hip/hip_runtime.h>

// ExtractFeatureMap: N1=2048 coarse voxels, N2=32768 fine voxels, F=64,
// SPATIAL=512, i=3 (scale=8, coarse_size=64).
//
// Key identity: the reference's 4-dim containment test
//   fm*scale <= c  &&  c < fm*scale + scale   (all integer-valued floats)
// is exactly  pack(fm) == pack(floor(c/scale))  per dimension. So instead of
// the (N1 x N2) brute force or a dense 64^3 scatter grid (3 dispatches), we
// fuse everything into ONE dispatch: stage the 2048 packed coarse cell-ids
// in LDS (8 KB), scan them per fine voxel, then gather. No workspace, no
// atomics, deterministic first-match (min index) == argmax-first semantics.

#define N1    2048
#define N2    32768
#define F     64
#define VPB   32          // fine voxels per block
#define TPV   8           // threads cooperating per voxel
#define BLOCK 256
#define NBLOCKS (N2 / VPB)   // 1024 blocks -> 4 blocks/CU, 16 waves/CU

__global__ __launch_bounds__(BLOCK)
void efm_fused(const float* __restrict__ fm,
               const float* __restrict__ xf,
               const float* __restrict__ co,
               const int*   __restrict__ ip,
               float* __restrict__ out_coords,
               float* __restrict__ out_feats) {
    __shared__ int cells[N1];     // packed coarse cell ids
    __shared__ int selArr[VPB];   // selected coarse index per voxel

    const int t = threadIdx.x;
    const int i = ip[0];

    // --- Stage: pack fm rows into LDS. Coalesced float4 reads. ---
    #pragma unroll
    for (int r = t; r < N1; r += BLOCK) {
        float4 f = ((const float4*)fm)[r];
        int id = ((((((int)f.w << 6) | (int)f.x) << 6) | (int)f.y) << 6) | (int)f.z;
        cells[r] = id;
    }
    __syncthreads();

    // --- Scan: 8 threads per voxel, each scans 256 cells as 64 x int4.
    // cells4[k*8+sub]: 8 distinct 16B addresses per wave (banks 4*sub..4*sub+3
    // cover all 32 banks), broadcast across the 8 voxel-groups -> conflict-free.
    const int vox  = t >> 3;   // 0..31
    const int sub  = t & 7;    // 0..7
    const int gvox = blockIdx.x * VPB + vox;

    float4 c = ((const float4*)co)[gvox];
    int cid = (((((((int)c.w >> i) << 6) | ((int)c.x >> i)) << 6)
                 | ((int)c.y >> i)) << 6) | ((int)c.z >> i);

    int local = N1;   // sentinel: no match
    const int4* cells4 = (const int4*)cells;
    #pragma unroll 4
    for (int k = 0; k < N1 / (4 * TPV); ++k) {   // 64 iters
        int idx4 = k * TPV + sub;
        int4 v = cells4[idx4];
        int j = idx4 * 4;
        if (v.x == cid) local = min(local, j);
        if (v.y == cid) local = min(local, j + 1);
        if (v.z == cid) local = min(local, j + 2);
        if (v.w == cid) local = min(local, j + 3);
    }
    // min-reduce across the 8 subs (consecutive lanes) of this voxel
    local = min(local, __shfl_down(local, 4, 8));
    local = min(local, __shfl_down(local, 2, 8));
    local = min(local, __shfl_down(local, 1, 8));
    if (sub == 0) selArr[vox] = (local < N1) ? local : 0;  // argmax(all-False)=0
    __syncthreads();

    // --- Gather: wave w handles voxels [w*8, w*8+8). Lane l reads/writes
    // feature l: 256B coalesced per voxel; selArr read is an LDS broadcast. ---
    const int lane = t & 63;
    const int wv   = t >> 6;
    #pragma unroll
    for (int v = 0; v < 8; ++v) {
        int lv  = wv * 8 + v;
        int sel = selArr[lv];
        out_feats[(size_t)(blockIdx.x * VPB + lv) * F + lane] = xf[sel * F + lane];
    }
    // coords: threads 0..127 write the 32 voxels' 4 floats, coalesced
    if (t < VPB * 4) {
        int lv = t >> 2, comp = t & 3;
        int sel = selArr[lv];
        out_coords[(blockIdx.x * VPB + lv) * 4 + comp] = fm[sel * 4 + comp];
    }
}

extern "C" void kernel_launch(void* const* d_in, const int* in_sizes, int n_in,
                              void* d_out, int out_size, void* d_ws, size_t ws_size,
                              hipStream_t stream) {
    const float* fm = (const float*)d_in[0];   // feature_map (N1,4) fp32
    const float* xf = (const float*)d_in[1];   // x_features  (N1,F) fp32
    const float* co = (const float*)d_in[2];   // coords      (N2,4) fp32
    const int*   ip = (const int*)d_in[3];     // i (scalar int32)

    float* out_coords = (float*)d_out;           // (N2,4) first
    float* out_feats  = (float*)d_out + N2 * 4;  // (N2,F) second

    efm_fused<<<NBLOCKS, BLOCK, 0, stream>>>(fm, xf, co, ip, out_coords, out_feats);
}